// Round 1
// baseline (87.007 us; speedup 1.0000x reference)
//
#include <hip/hip_runtime.h>

// KAN layer: out[b,o] = sum_i [ sum_g w[o,i,g]*exp(-|tanh(x[b,i])-grid[g]|*s[o,i])
//                               + ba[o,i]*tanh(x[b,i]) ]
// Factorized: per (o,i) prefix/suffix tables over g; per (b,o,i) only 2 exp2's.

#define B_   256
#define OUT_ 256
#define IN_  256
#define G_   8
#define NK   5          // k' = k-2, k in [2,6] since xn=tanh in (-1,1)
#define SCH  32         // i-chunks (split-K over i)
#define BT   8          // b's per block held in registers
#define ICH  (IN_/SCH)  // 8 i per chunk

// ---------------------------------------------------------------------------
// Kernel 1 (fused prep): part A computes xn=tanh(x) and the table-row index
// for each (b,i); part B builds per-(o,i) prefix/suffix tables, transposed
// to [k'][i][o] so the main kernel reads coalesced in o.
// ---------------------------------------------------------------------------
__global__ void kan_prep(const float* __restrict__ x,
                         const float* __restrict__ w,
                         const float* __restrict__ sc,
                         const float* __restrict__ ba,
                         const float* __restrict__ grid,
                         float2* __restrict__ xnk,
                         float2* __restrict__ sbt,
                         float2* __restrict__ T)
{
    const int idx = blockIdx.x * 256 + threadIdx.x;

    float g[G_];
#pragma unroll
    for (int j = 0; j < G_; ++j) g[j] = grid[j];   // broadcast loads

    // ---- part A: one (b,i) per thread (b = idx>>8, i = idx&255), coalesced
    {
        const float xv = x[idx];
        const float xn = tanhf(xv);
        int k = 0;
#pragma unroll
        for (int j = 0; j < G_; ++j) k += (g[j] <= xn) ? 1 : 0;
        k = min(max(k, 2), 6) - 2;                 // 0..4 (xn in [-1,1] => k in [2,6])
        const int row = k * IN_ + (idx & 255);     // precomputed table row
        xnk[idx] = make_float2(xn, __int_as_float(row));
    }

    // ---- part B: one (o,i) per thread, o = idx>>8 so input reads coalesce
    {
        const int o = idx >> 8;
        const int i = idx & 255;
        const int base = o * IN_ + i;
        const float s  = sc[base];
        const float bv = ba[base];

        float Ep[G_], Em[G_];
#pragma unroll
        for (int j = 0; j < G_; ++j) {
            const float wv = w[base * G_ + j];
            const float t  = s * g[j];
            Ep[j] = wv * expf(t);                  // for grid points below xn
            Em[j] = wv * expf(-t);                 // for grid points above xn
        }
#pragma unroll
        for (int kk = 0; kk < NK; ++kk) {
            const int k = kk + 2;
            float A = 0.f, Bv = 0.f;
#pragma unroll
            for (int j = 0; j < G_; ++j) {
                if (j < k) A += Ep[j]; else Bv += Em[j];   // compile-time split
            }
            T[(kk * IN_ + i) * OUT_ + o] = make_float2(A, Bv);
        }
        sbt[i * OUT_ + o] = make_float2(s * 1.44269504088896340736f, bv);
    }
}

// ---------------------------------------------------------------------------
// Kernel 2 (main): block = 256 o-lanes; loops BT=8 b's in registers over an
// i-chunk of 8. Per (b,o,i): 2 coalesced float2 loads + 2 exp2 + 4 fma.
// Partials per i-chunk written to workspace (no atomics).
// ---------------------------------------------------------------------------
__global__ __launch_bounds__(256, 4) void kan_main(
        const float2* __restrict__ xnk,
        const float2* __restrict__ sbt,
        const float2* __restrict__ T,
        float* __restrict__ partial)
{
    const int o    = threadIdx.x;
    const int bgrp = blockIdx.x & 31;   // 32 b-groups of BT
    const int ic   = blockIdx.x >> 5;   // 32 i-chunks of ICH
    const int b0   = bgrp * BT;
    const int i0   = ic * ICH;

    __shared__ float2 sxnk[BT][ICH];
    if (threadIdx.x < BT * ICH) {
        const int bb = threadIdx.x / ICH;
        const int ii = threadIdx.x % ICH;
        sxnk[bb][ii] = xnk[(b0 + bb) * IN_ + i0 + ii];
    }
    __syncthreads();

    float acc[BT];
#pragma unroll
    for (int j = 0; j < BT; ++j) acc[j] = 0.f;

    for (int ii = 0; ii < ICH; ++ii) {
        const int i = i0 + ii;
        const float2 sb = sbt[i * OUT_ + o];       // (c = s*log2e, ba) coalesced
#pragma unroll
        for (int bb = 0; bb < BT; ++bb) {
            const float2 xk = sxnk[bb][ii];        // LDS broadcast (wave-uniform)
            const float xn  = xk.x;
            const int   row = __float_as_int(xk.y);
            const float2 rec = T[(row << 8) + o];  // coalesced 512B/wave, L2-hot
            const float t = sb.x * xn;
            const float P = exp2f(-t);             // exp(-s*xn)
            const float M = exp2f(t);              // exp(+s*xn)
            float a = fmaf(sb.y, xn, acc[bb]);     // + ba*xn
            a       = fmaf(P, rec.x, a);           // + P*A[k]
            acc[bb] = fmaf(M, rec.y, a);           // + M*B[k]
        }
    }

    float* pout = partial + (size_t)ic * (B_ * OUT_) + b0 * OUT_ + o;
#pragma unroll
    for (int bb = 0; bb < BT; ++bb) pout[bb * OUT_] = acc[bb];   // coalesced
}

// ---------------------------------------------------------------------------
// Kernel 3: reduce the SCH partials per output. Fully overwrites d_out.
// ---------------------------------------------------------------------------
__global__ void kan_reduce(const float* __restrict__ partial,
                           float* __restrict__ out)
{
    const int idx = blockIdx.x * 256 + threadIdx.x;
    float s = 0.f;
#pragma unroll
    for (int c = 0; c < SCH; ++c) s += partial[c * (B_ * OUT_) + idx];
    out[idx] = s;
}

// ---------------------------------------------------------------------------
extern "C" void kernel_launch(void* const* d_in, const int* in_sizes, int n_in,
                              void* d_out, int out_size, void* d_ws, size_t ws_size,
                              hipStream_t stream)
{
    const float* x    = (const float*)d_in[0];
    const float* w    = (const float*)d_in[1];   // (OUT, IN, G)
    const float* sc   = (const float*)d_in[2];   // (OUT, IN)
    const float* ba   = (const float*)d_in[3];   // (OUT, IN)
    const float* grid = (const float*)d_in[4];   // (G)
    float* out = (float*)d_out;

    // workspace layout (total ~11.5 MB):
    //   xnk     : [B*IN]  float2   512 KB
    //   sbt     : [IN*OUT] float2  512 KB
    //   T       : [NK][IN][OUT] float2  2.5 MB
    //   partial : [SCH][B*OUT] float    8 MB
    char* ws = (char*)d_ws;
    float2* xnk = (float2*)(ws);
    float2* sbt = (float2*)(ws + 512 * 1024);
    float2* T   = (float2*)(ws + 1024 * 1024);
    float*  partial = (float*)(ws + 1024 * 1024 + (size_t)NK * IN_ * OUT_ * sizeof(float2));

    kan_prep<<<(B_ * IN_) / 256, 256, 0, stream>>>(x, w, sc, ba, grid, xnk, sbt, T);
    kan_main<<<SCH * (B_ / BT), 256, 0, stream>>>(xnk, sbt, T, partial);
    kan_reduce<<<(B_ * OUT_) / 256, 256, 0, stream>>>(partial, out);
}

// Round 2
// 83.665 us; speedup vs baseline: 1.0399x; 1.0399x over previous
//
#include <hip/hip_runtime.h>

// KAN layer: out[b,o] = sum_i [ sum_g w[o,i,g]*exp(-|tanh(x[b,i])-grid[g]|*s[o,i])
//                               + ba[o,i]*tanh(x[b,i]) ]
// Factorization: exp(-s|xn-g|) = exp(-s*xn)*[w*e^{s*g}]      (g <= xn)
//                              = exp(+s*xn)*[w*e^{-s*g}]     (g >  xn)
// Per (o,i) prefix/suffix tables over the 5 possible split points k (xn in
// (-1,1) => k in [2,6]); per (b,o,i) only 2 exp2's + 3 fma + one 8B table read.

#define B_   256
#define OUT_ 256
#define IN_  256
#define G_   8
#define NK   5          // k' = k-2
#define BT   2          // b's per main block (register-blocked)
#define OT   64         // o-tile per main block (one wave-width)

// ---------------------------------------------------------------------------
// Kernel 1 (prep), grid 256 x 256:
//  part A: idx=(b,i) i-fast  -> xn=tanh(x), table row index. Coalesced R/W.
//  part B: i=blockIdx, o=tid -> per-(o,i) tables, stores coalesced 512B/wave
//          (T layout [k'][i][o], o fast, matching the main kernel's reads).
// ---------------------------------------------------------------------------
__global__ void kan_prep(const float* __restrict__ x,
                         const float* __restrict__ w,
                         const float* __restrict__ sc,
                         const float* __restrict__ ba,
                         const float* __restrict__ grid,
                         float2* __restrict__ xnk,
                         float2* __restrict__ sbt,
                         float2* __restrict__ T)
{
    float g[G_];
#pragma unroll
    for (int j = 0; j < G_; ++j) g[j] = grid[j];   // uniform broadcast loads

    // ---- part A: one (b,i) per thread, i fast -> coalesced
    {
        const int idx = blockIdx.x * 256 + threadIdx.x;
        const float xn = tanhf(x[idx]);
        int k = 0;
#pragma unroll
        for (int j = 0; j < G_; ++j) k += (g[j] <= xn) ? 1 : 0;
        k = min(max(k, 2), 6) - 2;                 // 0..4
        const int row = k * IN_ + (idx & (IN_ - 1));
        xnk[idx] = make_float2(xn, __int_as_float(row));
    }

    // ---- part B: one i per block, o = tid -> all stores coalesced
    {
        const int i = blockIdx.x;
        const int o = threadIdx.x;
        const int base = o * IN_ + i;              // strided reads (L2-hot, cheap)
        const float s  = sc[base];
        const float bv = ba[base];

        float Ep[G_], Em[G_];
#pragma unroll
        for (int j = 0; j < G_; ++j) {
            const float wv = w[base * G_ + j];     // 32B contiguous per thread
            const float t  = s * g[j];
            Ep[j] = wv * __expf(t);
            Em[j] = wv * __expf(-t);
        }
#pragma unroll
        for (int kk = 0; kk < NK; ++kk) {
            const int k = kk + 2;
            float A = 0.f, Bv = 0.f;
#pragma unroll
            for (int j = 0; j < G_; ++j) {
                if (j < k) A += Ep[j]; else Bv += Em[j];   // compile-time split
            }
            T[(kk * IN_ + i) * OUT_ + o] = make_float2(A, Bv);  // 512B/wave
        }
        sbt[i * OUT_ + o] = make_float2(s * 1.44269504088896340736f, bv);
    }
}

// ---------------------------------------------------------------------------
// Kernel 2 (main): grid = (B/BT) x (OUT/OT) = 512 blocks, 256 threads.
// Block = 4 waves; wave ig owns i in [ig*64, ig*64+64), 64 o-lanes, BT b's.
// Full i-reduction inside the block via 2KB LDS tree -> direct d_out store.
// ---------------------------------------------------------------------------
__global__ __launch_bounds__(256, 8) void kan_main(
        const float2* __restrict__ xnk,
        const float2* __restrict__ sbt,
        const float2* __restrict__ T,
        float* __restrict__ out)
{
    const int lane = threadIdx.x & 63;
    const int igrp = threadIdx.x >> 6;          // 0..3
    const int ot   = blockIdx.x & 3;            // 4 o-tiles
    const int bg   = blockIdx.x >> 2;           // 128 b-groups
    const int o    = ot * OT + lane;
    const int b0   = bg * BT;

    __shared__ float2 sxk[BT * IN_];            // 4 KB: xn+row for our b's
    __shared__ float  sacc[4][BT][OT];          // 2 KB: per-wave partials

    for (int t = threadIdx.x; t < BT * IN_; t += 256)
        sxk[t] = xnk[b0 * IN_ + t];             // coalesced
    __syncthreads();

    float acc[BT];
#pragma unroll
    for (int bb = 0; bb < BT; ++bb) acc[bb] = 0.f;

    const int i0 = igrp * 64;
    for (int ii = 0; ii < 64; ++ii) {
        const int i = i0 + ii;
        const float2 sb = sbt[i * OUT_ + o];    // 512B/wave, L2-hot
#pragma unroll
        for (int bb = 0; bb < BT; ++bb) {
            const float2 xk = sxk[bb * IN_ + i];  // wave-uniform LDS broadcast
            const float xn  = xk.x;
            const int   row = __float_as_int(xk.y);
            const float2 rec = T[(row << 8) + o]; // 512B/wave, L2/L1-hot
            const float t = sb.x * xn;            // t = s*log2e*xn
            float a = fmaf(sb.y, xn, acc[bb]);    // + ba*xn
            a       = fmaf(exp2f(-t), rec.x, a);  // + e^{-s*xn} * A[k]
            acc[bb] = fmaf(exp2f(t),  rec.y, a);  // + e^{+s*xn} * B[k]
        }
    }

#pragma unroll
    for (int bb = 0; bb < BT; ++bb) sacc[igrp][bb][lane] = acc[bb];
    __syncthreads();

    if (threadIdx.x < BT * OT) {
        const int bb = threadIdx.x >> 6;
        const int l  = threadIdx.x & 63;
        const float s = sacc[0][bb][l] + sacc[1][bb][l]
                      + sacc[2][bb][l] + sacc[3][bb][l];
        out[(b0 + bb) * OUT_ + ot * OT + l] = s;  // coalesced, full overwrite
    }
}

// ---------------------------------------------------------------------------
extern "C" void kernel_launch(void* const* d_in, const int* in_sizes, int n_in,
                              void* d_out, int out_size, void* d_ws, size_t ws_size,
                              hipStream_t stream)
{
    const float* x    = (const float*)d_in[0];
    const float* w    = (const float*)d_in[1];   // (OUT, IN, G)
    const float* sc   = (const float*)d_in[2];   // (OUT, IN)
    const float* ba   = (const float*)d_in[3];   // (OUT, IN)
    const float* grid = (const float*)d_in[4];   // (G)
    float* out = (float*)d_out;

    // workspace: xnk 512KB | sbt 512KB | T 2.5MB   (total 3.5 MB)
    char* ws = (char*)d_ws;
    float2* xnk = (float2*)(ws);
    float2* sbt = (float2*)(ws + 512 * 1024);
    float2* T   = (float2*)(ws + 1024 * 1024);

    kan_prep<<<IN_, 256, 0, stream>>>(x, w, sc, ba, grid, xnk, sbt, T);
    kan_main<<<(B_ / BT) * (OUT_ / OT), 256, 0, stream>>>(xnk, sbt, T, out);
}